// Round 1
// baseline (602.737 us; speedup 1.0000x reference)
//
#include <hip/hip_runtime.h>
#include <cstdint>
#include <math.h>

typedef float f32x4 __attribute__((ext_vector_type(4)));
typedef __bf16 bf16x8 __attribute__((ext_vector_type(8)));
typedef unsigned short us4 __attribute__((ext_vector_type(4)));
typedef unsigned short us8 __attribute__((ext_vector_type(8)));

#define DEV static __device__ __forceinline__

DEV unsigned short f2bf(float f){
  unsigned int u = __float_as_uint(f);
  u += 0x7fffu + ((u >> 16) & 1u);
  return (unsigned short)(u >> 16);
}

DEV void gload16(const void* g, void* l){
  __builtin_amdgcn_global_load_lds((__attribute__((address_space(1))) void*)g,
                                   (__attribute__((address_space(3))) void*)l, 16, 0, 0);
}

// ---------------- RMSNorm (block = 1 token row of 1024) ----------------
__global__ __launch_bounds__(256) void rmsnorm_kernel(const float* __restrict__ x, const float* __restrict__ w,
    unsigned short* __restrict__ ob, float* __restrict__ of){
  int t = blockIdx.x, tid = threadIdx.x;
  float4 xv = *(const float4*)(x + (long long)t*1024 + tid*4);
  float ss = xv.x*xv.x + xv.y*xv.y + xv.z*xv.z + xv.w*xv.w;
  for (int m=32;m;m>>=1) ss += __shfl_xor(ss,m);
  __shared__ float lds[4];
  if ((tid&63)==0) lds[tid>>6] = ss;
  __syncthreads();
  float tot = lds[0]+lds[1]+lds[2]+lds[3];
  float inv = rsqrtf(tot*(1.0f/1024.0f) + 1.1920928955078125e-07f);
  float4 wv = *(const float4*)(w + tid*4);
  float r0 = xv.x*inv*wv.x, r1 = xv.y*inv*wv.y, r2 = xv.z*inv*wv.z, r3 = xv.w*inv*wv.w;
  us4 rb = { f2bf(r0), f2bf(r1), f2bf(r2), f2bf(r3) };
  *(us4*)&ob[(long long)t*1024 + tid*4] = rb;
  if (of){
    float4 rf; rf.x=r0; rf.y=r1; rf.z=r2; rf.w=r3;
    *(float4*)(of + (long long)t*1024 + tid*4) = rf;
  }
}

// ---------------- generic bf16 GEMM  C[M,N] = A[M,K] * B[N,K]^T ----------------
// A: bf16 (gather-able rows). B: fp32, reg-staged + converted. 128x128 tile, BK=64.
// EPI: 0 = store fp32, 1 = fp32 + resid, 2 = bf16 gelu -> Cb (rows rbase+lr),
//      3 = fp32 acc*wgt[gi] scattered to Cf[tok_slot*ldc]
template<int EPI, bool GATHER>
__global__ __launch_bounds__(256) void gemm_bt(
    const unsigned short* __restrict__ A, int lda,
    const float* __restrict__ Bw, long long bstride, int ldb,
    int M, int N, int K,
    const int* __restrict__ counts, const int* __restrict__ offs,
    const int* __restrict__ tok_list, const float* __restrict__ wgt,
    const float* __restrict__ resid,
    float* __restrict__ Cf, unsigned short* __restrict__ Cb, int ldc)
{
  const int e = blockIdx.z;
  const int Me = counts ? counts[e] : M;
  const int by = blockIdx.y;
  if (by * 128 >= Me) return;
  const int rbase = offs ? offs[e] : 0;
  const int bx = blockIdx.x;
  const float* B = Bw + (long long)e * bstride;

  __shared__ __align__(16) unsigned short As[128*64];
  __shared__ __align__(16) unsigned short Bs[128*64];

  const int tid = threadIdx.x, lane = tid & 63, w = tid >> 6;
  const int wr = w >> 1, wc = w & 1;

  // A staging source pointers (pre-swizzled source so linear global_load_lds
  // dest lands in XOR-swizzled layout: chunk' = chunk ^ (row&7))
  const unsigned short* asrc[4];
  #pragma unroll
  for (int i = 0; i < 4; ++i){
    int seg = 4*i + w;
    int row = seg*8 + (lane>>3);
    int cs = (lane & 7) ^ (row & 7);
    int lr = by*128 + row; if (lr > Me-1) lr = Me-1;
    int li = rbase + lr;
    int ar = GATHER ? (tok_list[li] >> 1) : li;
    asrc[i] = A + (long long)ar * lda + cs*8;
  }
  const int brow = tid >> 1;
  const int bh = (tid & 1) * 32;
  const float* bsrc = B + (long long)(bx*128 + brow) * ldb + bh;

  f32x4 acc[4][4] = {};

  for (int k0 = 0; k0 < K; k0 += 64){
    __syncthreads();
    #pragma unroll
    for (int i = 0; i < 4; ++i){
      int seg = 4*i + w;
      gload16(asrc[i] + k0, &As[seg*512]);
    }
    {
      const float4* s4 = (const float4*)(bsrc + k0);
      float bvv[32];
      #pragma unroll
      for (int j=0;j<8;++j) *(float4*)&bvv[j*4] = s4[j];
      #pragma unroll
      for (int cj=0;cj<4;++cj){
        union { unsigned short u[8]; us8 v; } U;
        #pragma unroll
        for (int u2=0;u2<8;++u2) U.u[u2] = f2bf(bvv[cj*8+u2]);
        int chunk = (bh>>3) + cj;
        int sc = chunk ^ (brow & 7);
        *(us8*)&Bs[brow*64 + sc*8] = U.v;
      }
    }
    __syncthreads();
    #pragma unroll
    for (int kk=0;kk<2;++kk){
      bf16x8 af[4], bfr[4];
      #pragma unroll
      for (int m=0;m<4;++m){
        int R = wr*64 + m*16 + (lane&15);
        int ch = ((lane>>4) + 4*kk) ^ (R&7);
        af[m] = *(const bf16x8*)&As[R*64 + ch*8];
      }
      #pragma unroll
      for (int n=0;n<4;++n){
        int R = wc*64 + n*16 + (lane&15);
        int ch = ((lane>>4) + 4*kk) ^ (R&7);
        bfr[n] = *(const bf16x8*)&Bs[R*64 + ch*8];
      }
      #pragma unroll
      for (int m=0;m<4;++m)
        #pragma unroll
        for (int n=0;n<4;++n)
          acc[m][n] = __builtin_amdgcn_mfma_f32_16x16x32_bf16(af[m], bfr[n], acc[m][n], 0, 0, 0);
    }
  }

  #pragma unroll
  for (int m=0;m<4;++m){
    #pragma unroll
    for (int r=0;r<4;++r){
      int lr = by*128 + wr*64 + m*16 + 4*(lane>>4) + r;
      if (lr >= Me) continue;
      #pragma unroll
      for (int n=0;n<4;++n){
        int col = bx*128 + wc*64 + n*16 + (lane&15);
        float v = acc[m][n][r];
        if constexpr (EPI == 0){
          Cf[(long long)lr*ldc + col] = v;
        } else if constexpr (EPI == 1){
          Cf[(long long)lr*ldc + col] = v + resid[(long long)lr*ldc + col];
        } else if constexpr (EPI == 2){
          float g = 0.5f * v * (1.0f + erff(v * 0.70710678118654752f));
          Cb[(long long)(rbase+lr)*ldc + col] = f2bf(g);
        } else {
          int gi = rbase + lr;
          int ts = tok_list[gi];
          Cf[(long long)ts*ldc + col] = v * wgt[gi];
        }
      }
    }
  }
}

// ---------------- RoPE + bf16 cast of q,k,v ----------------
__global__ __launch_bounds__(256) void rope_kernel(const float* __restrict__ qkv,
    unsigned short* __restrict__ q, unsigned short* __restrict__ k, unsigned short* __restrict__ v){
  int t = blockIdx.x, tid = threadIdx.x;
  const float* row = qkv + (long long)t*3072;
  float4 vv = *(const float4*)(row + 2048 + tid*4);
  us4 pv = { f2bf(vv.x), f2bf(vv.y), f2bf(vv.z), f2bf(vv.w) };
  *(us4*)&v[(long long)t*1024 + tid*4] = pv;
  #pragma unroll
  for (int u2=0; u2<2; ++u2){
    int pid = tid + u2*256;
    int hh = pid >> 5, j = pid & 31;
    float invf = expf(-(float)j * 0.28782313662425575f); // 10000^{-j/32}
    float fr = (float)t * invf;
    float sn, cs;
    sincosf(fr, &sn, &cs);
    int base = hh*64 + j;
    long long ob_ = (long long)t*1024 + base;
    float a = row[base], b = row[base+32];
    q[ob_]    = f2bf(a*cs - b*sn);
    q[ob_+32] = f2bf(b*cs + a*sn);
    a = row[1024+base]; b = row[1024+base+32];
    k[ob_]    = f2bf(a*cs - b*sn);
    k[ob_+32] = f2bf(b*cs + a*sn);
  }
}

// ---------------- causal flash attention ----------------
// grid (S/64, H), block 256 (4 waves x 16 q-rows). K/V 64x64 tiles in swizzled LDS.
__global__ __launch_bounds__(256) void attn_kernel(
    const unsigned short* __restrict__ Q,
    const unsigned short* __restrict__ K,
    const unsigned short* __restrict__ V,
    unsigned short* __restrict__ O)
{
  const int bx = blockIdx.x, h = blockIdx.y;
  const int q0 = bx*64;
  const int tid = threadIdx.x, lane = tid&63, w = tid>>6;

  __shared__ __align__(16) unsigned short Ks[64*64];
  __shared__ __align__(16) unsigned short Vs[64*64];
  __shared__ __align__(16) unsigned short Ps[4*16*64];
  unsigned short* Pw = Ps + w*1024;

  const int qrow = q0 + w*16 + (lane&15);
  bf16x8 aq[2];
  #pragma unroll
  for (int kk=0;kk<2;++kk)
    aq[kk] = *(const bf16x8*)&Q[((long long)qrow*16 + h)*64 + 32*kk + 8*(lane>>4)];

  f32x4 o[4] = {};
  float Mx[4] = {-INFINITY,-INFINITY,-INFINITY,-INFINITY};
  float Ls[4] = {0.f,0.f,0.f,0.f};

  const int row_g = q0 + w*16 + 4*(lane>>4); // + r
  const int nt = bx + 1;
  for (int it = 0; it < nt; ++it){
    int k0 = it*64;
    #pragma unroll
    for (int i=0;i<2;++i){
      int seg = 4*i + w;
      int row = seg*8 + (lane>>3);
      int cs = (lane&7) ^ (row&7);
      long long gofs = ((long long)(k0+row)*16 + h)*64 + cs*8;
      gload16(&K[gofs], &Ks[seg*512]);
      gload16(&V[gofs], &Vs[seg*512]);
    }
    __syncthreads();
    f32x4 st[4];
    #pragma unroll
    for (int kt=0;kt<4;++kt){
      f32x4 s = {0.f,0.f,0.f,0.f};
      #pragma unroll
      for (int kk=0;kk<2;++kk){
        int R = kt*16 + (lane&15);
        int ch = ((lane>>4)+4*kk) ^ (R&7);
        bf16x8 bk = *(const bf16x8*)&Ks[R*64 + ch*8];
        s = __builtin_amdgcn_mfma_f32_16x16x32_bf16(aq[kk], bk, s, 0,0,0);
      }
      st[kt] = s;
    }
    #pragma unroll
    for (int kt=0;kt<4;++kt){
      int col = k0 + kt*16 + (lane&15);
      #pragma unroll
      for (int r=0;r<4;++r){
        float vv = st[kt][r]*0.125f;
        st[kt][r] = (col <= row_g + r) ? vv : -INFINITY;
      }
    }
    float sf[4];
    #pragma unroll
    for (int r=0;r<4;++r){
      float mx = fmaxf(fmaxf(st[0][r],st[1][r]),fmaxf(st[2][r],st[3][r]));
      mx = fmaxf(mx, __shfl_xor(mx,1));
      mx = fmaxf(mx, __shfl_xor(mx,2));
      mx = fmaxf(mx, __shfl_xor(mx,4));
      mx = fmaxf(mx, __shfl_xor(mx,8));
      float mn = fmaxf(Mx[r], mx);
      float sc = __expf(Mx[r]-mn);
      Mx[r]=mn; sf[r]=sc;
      float ls=0.f;
      #pragma unroll
      for (int kt=0;kt<4;++kt){ float pp = __expf(st[kt][r]-mn); st[kt][r]=pp; ls+=pp; }
      Ls[r] = Ls[r]*sc + ls;
    }
    #pragma unroll
    for (int dt=0;dt<4;++dt)
      #pragma unroll
      for (int r=0;r<4;++r) o[dt][r] *= sf[r];
    // P -> per-wave swizzled LDS (bf16)
    #pragma unroll
    for (int kt=0;kt<4;++kt)
      #pragma unroll
      for (int r=0;r<4;++r){
        int prow = 4*(lane>>4)+r, pcol = kt*16+(lane&15);
        int byteoff = (prow*128 + pcol*2) ^ ((prow&7)<<4);
        *(unsigned short*)((char*)Pw + byteoff) = f2bf(st[kt][r]);
      }
    bf16x8 pa[2];
    #pragma unroll
    for (int kk=0;kk<2;++kk){
      int pr = lane&15;
      int ch = ((lane>>4)+4*kk) ^ (pr&7);
      pa[kk] = *(const bf16x8*)&Pw[pr*64 + ch*8];
    }
    #pragma unroll
    for (int dt=0;dt<4;++dt){
      #pragma unroll
      for (int kk=0;kk<2;++kk){
        union { unsigned short u[8]; bf16x8 v; } Ub;
        #pragma unroll
        for (int j=0;j<8;++j){
          int kr = 32*kk + 8*(lane>>4) + j;
          int d = dt*16 + (lane&15);
          int byteoff = (kr*128 + d*2) ^ ((kr&7)<<4);
          Ub.u[j] = *(const unsigned short*)((const char*)Vs + byteoff);
        }
        o[dt] = __builtin_amdgcn_mfma_f32_16x16x32_bf16(pa[kk], Ub.v, o[dt], 0,0,0);
      }
    }
    __syncthreads();
  }
  #pragma unroll
  for (int r=0;r<4;++r){
    float l = Ls[r];
    l += __shfl_xor(l,1); l += __shfl_xor(l,2); l += __shfl_xor(l,4); l += __shfl_xor(l,8);
    Ls[r] = 1.0f / l;
  }
  #pragma unroll
  for (int dt=0;dt<4;++dt)
    #pragma unroll
    for (int r=0;r<4;++r){
      float vv = o[dt][r]*Ls[r];
      int rg = row_g + r;
      O[(long long)rg*1024 + h*64 + dt*16 + (lane&15)] = f2bf(vv);
    }
}

// ---------------- router + top2 ----------------
__global__ __launch_bounds__(256) void router_kernel(const float* __restrict__ h2f, const float* __restrict__ rw,
    float* __restrict__ probs, int* __restrict__ tope, float* __restrict__ topw, int* __restrict__ counts){
  int t = blockIdx.x, tid = threadIdx.x;
  float4 hv = *(const float4*)(h2f + (long long)t*1024 + tid*4);
  float pe[8];
  #pragma unroll
  for (int e2=0;e2<8;++e2){
    float4 wv = *(const float4*)(rw + e2*1024 + tid*4);
    pe[e2] = hv.x*wv.x + hv.y*wv.y + hv.z*wv.z + hv.w*wv.w;
  }
  __shared__ float lds[32];
  #pragma unroll
  for (int e2=0;e2<8;++e2){
    float v = pe[e2];
    for (int m=32;m;m>>=1) v += __shfl_xor(v,m);
    if ((tid&63)==0) lds[(tid>>6)*8+e2] = v;
  }
  __syncthreads();
  if (tid==0){
    float lg[8], pp[8];
    #pragma unroll
    for (int e2=0;e2<8;++e2) lg[e2] = lds[e2]+lds[8+e2]+lds[16+e2]+lds[24+e2];
    float mx = lg[0];
    for (int e2=1;e2<8;++e2) mx = fmaxf(mx, lg[e2]);
    float s = 0.f;
    for (int e2=0;e2<8;++e2){ pp[e2] = __expf(lg[e2]-mx); s += pp[e2]; }
    float inv = 1.0f/s;
    int i0 = 0;
    for (int e2=1;e2<8;++e2) if (pp[e2] > pp[i0]) i0 = e2;
    int i1 = (i0==0)?1:0;
    for (int e2=0;e2<8;++e2) if (e2!=i0 && pp[e2] > pp[i1]) i1 = e2;
    for (int e2=0;e2<8;++e2) probs[t*8+e2] = pp[e2]*inv;
    float p0 = pp[i0], p1 = pp[i1], wsum = p0+p1;
    tope[t*2] = i0; tope[t*2+1] = i1;
    topw[t*2] = p0/wsum; topw[t*2+1] = p1/wsum;
    atomicAdd(&counts[i0],1); atomicAdd(&counts[i1],1);
  }
}

__global__ void init_kernel(int* counts, int* cursor){
  int i = threadIdx.x;
  if (i<8){ counts[i]=0; cursor[i]=0; }
}

__global__ void prefix_kernel(const int* counts, int* offs){
  if (threadIdx.x==0){
    int a=0;
    for (int e2=0;e2<8;++e2){ offs[e2]=a; a+=counts[e2]; }
  }
}

__global__ void scatter_kernel(const int* __restrict__ tope, const float* __restrict__ topw,
    const int* __restrict__ offs, int* __restrict__ cursor, int* __restrict__ tok_list, float* __restrict__ wgt){
  int t = blockIdx.x*blockDim.x + threadIdx.x;
  if (t >= 2048) return;
  #pragma unroll
  for (int s=0;s<2;++s){
    int e2 = tope[t*2+s];
    int pos = atomicAdd(&cursor[e2], 1);
    int i = offs[e2] + pos;
    tok_list[i] = t*2+s;
    wgt[i] = topw[t*2+s];
  }
}

__global__ __launch_bounds__(256) void aux_kernel(const float* __restrict__ probs, float* __restrict__ out){
  int tid = threadIdx.x;
  float pe[8] = {0,0,0,0,0,0,0,0};
  for (int t = tid; t < 2048; t += 256){
    #pragma unroll
    for (int e2=0;e2<8;++e2) pe[e2] += probs[t*8+e2];
  }
  __shared__ float lds[32];
  #pragma unroll
  for (int e2=0;e2<8;++e2){
    float v = pe[e2];
    for (int m=32;m;m>>=1) v += __shfl_xor(v,m);
    if ((tid&63)==0) lds[(tid>>6)*8 + e2] = v;
  }
  __syncthreads();
  if (tid==0){
    float aux = 0.f;
    #pragma unroll
    for (int e2=0;e2<8;++e2){
      float mean = (lds[e2]+lds[8+e2]+lds[16+e2]+lds[24+e2]) * (1.0f/2048.0f);
      aux += mean*mean;
    }
    out[2097152] = 8.0f * aux;
  }
}

__global__ __launch_bounds__(256) void final_kernel(const float* __restrict__ x1, const float* __restrict__ slots, float* __restrict__ out){
  int t = blockIdx.x, tid = threadIdx.x;
  long long b = (long long)t*1024 + tid*4;
  float4 a  = *(const float4*)(x1 + b);
  float4 s0 = *(const float4*)(slots + (long long)t*2048 + tid*4);
  float4 s1 = *(const float4*)(slots + (long long)t*2048 + 1024 + tid*4);
  float4 rr; rr.x=a.x+s0.x+s1.x; rr.y=a.y+s0.y+s1.y; rr.z=a.z+s0.z+s1.z; rr.w=a.w+s0.w+s1.w;
  *(float4*)(out + b) = rr;
}

extern "C" void kernel_launch(void* const* d_in, const int* in_sizes, int n_in,
                              void* d_out, int out_size, void* d_ws, size_t ws_size,
                              hipStream_t stream)
{
  (void)in_sizes; (void)n_in; (void)out_size; (void)ws_size;
  const float* x    = (const float*)d_in[0];
  const float* qkvw = (const float*)d_in[1];
  const float* outw = (const float*)d_in[2];
  const float* rw   = (const float*)d_in[3];
  const float* w1   = (const float*)d_in[4];
  const float* w2   = (const float*)d_in[5];
  const float* n1w  = (const float*)d_in[6];
  const float* n2w  = (const float*)d_in[7];
  float* out = (float*)d_out;

  char* p = (char*)d_ws;
  auto alloc = [&](size_t b)->void*{ void* r = (void*)p; p += (b + 255) & ~(size_t)255; return r; };
  unsigned short* h_b  = (unsigned short*)alloc(2048ll*1024*2);
  unsigned short* qb   = (unsigned short*)alloc(2048ll*1024*2);
  unsigned short* kb   = (unsigned short*)alloc(2048ll*1024*2);
  unsigned short* vb   = (unsigned short*)alloc(2048ll*1024*2);
  unsigned short* ob   = (unsigned short*)alloc(2048ll*1024*2);
  unsigned short* h2b  = (unsigned short*)alloc(2048ll*1024*2);
  float* qkv   = (float*)alloc(2048ll*3072*4);
  float* x1    = (float*)alloc(2048ll*1024*4);
  float* h2f   = (float*)alloc(2048ll*1024*4);
  unsigned short* hid = (unsigned short*)alloc(4096ll*4096*2);
  float* slots = (float*)alloc(2048ll*2*1024*4);
  float* probs = (float*)alloc(2048ll*8*4);
  int*   tope  = (int*)alloc(2048*2*4);
  float* topw  = (float*)alloc(2048*2*4);
  int*   counts= (int*)alloc(64);
  int*   offs  = (int*)alloc(64);
  int*   cursor= (int*)alloc(64);
  int*   tok_list = (int*)alloc(4096*4);
  float* wgt   = (float*)alloc(4096*4);

  init_kernel<<<1,64,0,stream>>>(counts, cursor);
  rmsnorm_kernel<<<2048,256,0,stream>>>(x, n1w, h_b, nullptr);
  gemm_bt<0,false><<<dim3(24,16,1),256,0,stream>>>(h_b,1024, qkvw,0,1024, 2048,3072,1024,
      nullptr,nullptr,nullptr,nullptr,nullptr, qkv,nullptr,3072);
  rope_kernel<<<2048,256,0,stream>>>(qkv, qb, kb, vb);
  attn_kernel<<<dim3(32,16),256,0,stream>>>(qb,kb,vb,ob);
  gemm_bt<1,false><<<dim3(8,16,1),256,0,stream>>>(ob,1024, outw,0,1024, 2048,1024,1024,
      nullptr,nullptr,nullptr,nullptr, x, x1,nullptr,1024);
  rmsnorm_kernel<<<2048,256,0,stream>>>(x1, n2w, h2b, h2f);
  router_kernel<<<2048,256,0,stream>>>(h2f, rw, probs, tope, topw, counts);
  prefix_kernel<<<1,64,0,stream>>>(counts, offs);
  scatter_kernel<<<8,256,0,stream>>>(tope, topw, offs, cursor, tok_list, wgt);
  gemm_bt<2,true><<<dim3(32,16,8),256,0,stream>>>(h2b,1024, w1,(long long)4096*1024,1024, 2048,4096,1024,
      counts,offs,tok_list,nullptr,nullptr, nullptr,hid,4096);
  gemm_bt<3,false><<<dim3(8,16,8),256,0,stream>>>(hid,4096, w2,(long long)4096*1024,4096, 2048,1024,4096,
      counts,offs,tok_list,wgt,nullptr, slots,nullptr,1024);
  aux_kernel<<<1,256,0,stream>>>(probs, out);
  final_kernel<<<2048,256,0,stream>>>(x1, slots, out);
}

// Round 2
// 494.137 us; speedup vs baseline: 1.2198x; 1.2198x over previous
//
#include <hip/hip_runtime.h>
#include <cstdint>
#include <math.h>

typedef float f32x4 __attribute__((ext_vector_type(4)));
typedef __bf16 bf16x8 __attribute__((ext_vector_type(8)));
typedef unsigned short us4 __attribute__((ext_vector_type(4)));

#define DEV static __device__ __forceinline__

DEV unsigned short f2bf(float f){
  union { __bf16 h; unsigned short u; } cv; cv.h = (__bf16)f; return cv.u;
}
DEV float bf2f(unsigned short u){ return __uint_as_float((unsigned int)u << 16); }

DEV void gload16(const void* g, void* l){
  __builtin_amdgcn_global_load_lds((__attribute__((address_space(1))) void*)g,
                                   (__attribute__((address_space(3))) void*)l, 16, 0, 0);
}

// ---------------- RMSNorm 1 ----------------
__global__ __launch_bounds__(256) void rmsnorm_kernel(const float* __restrict__ x, const float* __restrict__ w,
    unsigned short* __restrict__ ob){
  int t = blockIdx.x, tid = threadIdx.x;
  float4 xv = *(const float4*)(x + (long long)t*1024 + tid*4);
  float ss = xv.x*xv.x + xv.y*xv.y + xv.z*xv.z + xv.w*xv.w;
  for (int m=32;m;m>>=1) ss += __shfl_xor(ss,m);
  __shared__ float lds[4];
  if ((tid&63)==0) lds[tid>>6] = ss;
  __syncthreads();
  float tot = lds[0]+lds[1]+lds[2]+lds[3];
  float inv = rsqrtf(tot*(1.0f/1024.0f) + 1.1920928955078125e-07f);
  float4 wv = *(const float4*)(w + tid*4);
  us4 rb = { f2bf(xv.x*inv*wv.x), f2bf(xv.y*inv*wv.y), f2bf(xv.z*inv*wv.z), f2bf(xv.w*inv*wv.w) };
  *(us4*)&ob[(long long)t*1024 + tid*4] = rb;
}

// ---------------- RMSNorm 2: sum two partials, write x1 fp32 + h2 bf16 + h2 fp32 ----------------
__global__ __launch_bounds__(256) void rmsnorm2_kernel(const float* __restrict__ xa, const float* __restrict__ xb,
    const float* __restrict__ w, float* __restrict__ x1, unsigned short* __restrict__ hb, float* __restrict__ hf){
  int t = blockIdx.x, tid = threadIdx.x;
  long long b = (long long)t*1024 + tid*4;
  float4 a = *(const float4*)(xa + b);
  float4 c = *(const float4*)(xb + b);
  float4 xv; xv.x=a.x+c.x; xv.y=a.y+c.y; xv.z=a.z+c.z; xv.w=a.w+c.w;
  *(float4*)(x1 + b) = xv;
  float ss = xv.x*xv.x + xv.y*xv.y + xv.z*xv.z + xv.w*xv.w;
  for (int m=32;m;m>>=1) ss += __shfl_xor(ss,m);
  __shared__ float lds[4];
  if ((tid&63)==0) lds[tid>>6] = ss;
  __syncthreads();
  float tot = lds[0]+lds[1]+lds[2]+lds[3];
  float inv = rsqrtf(tot*(1.0f/1024.0f) + 1.1920928955078125e-07f);
  float4 wv = *(const float4*)(w + tid*4);
  float r0 = xv.x*inv*wv.x, r1 = xv.y*inv*wv.y, r2 = xv.z*inv*wv.z, r3 = xv.w*inv*wv.w;
  us4 rb = { f2bf(r0), f2bf(r1), f2bf(r2), f2bf(r3) };
  *(us4*)&hb[b] = rb;
  float4 rf; rf.x=r0; rf.y=r1; rf.z=r2; rf.w=r3;
  *(float4*)(hf + b) = rf;
}

// ---------------- generic GEMM  C[M,N] = A[M,K](bf16) * B[N,K]^T(fp32) ----------------
// Both operands staged via global_load_lds with pre-swizzled source (XOR chunk^(row&7)).
// B is fp32 in LDS; converted to bf16 at fragment read (v_cvt_pk_bf16_f32).
// EPI: 1 = fp32 (+resid if ks==0) to Cf+ks*ksoff, 2 = gelu->bf16 Cb rows rbase+lr,
//      3 = fp32 acc*wgt scattered to Cf+ks*ksoff+tok_slot*ldc, 4 = plain bf16 to Cb
template<int EPI, bool GATHER>
__global__ __launch_bounds__(256) void gemm_bt(
    const unsigned short* __restrict__ A, int lda,
    const float* __restrict__ Bw, long long bstride, int ldb,
    int M, int N, int K, int KS, long long ksoff,
    const int* __restrict__ counts, const int* __restrict__ offs,
    const int* __restrict__ tok_list, const float* __restrict__ wgt,
    const float* __restrict__ resid,
    float* __restrict__ Cf, unsigned short* __restrict__ Cb, int ldc)
{
  const int z = blockIdx.z;
  const int e = z / KS, ks = z - e*KS;
  const int Me = counts ? counts[e] : M;
  const int by = blockIdx.y;
  if (by * 128 >= Me) return;
  const int rbase = offs ? offs[e] : 0;
  const int bx = blockIdx.x;
  const float* B = Bw + (long long)e * bstride;
  const int kbeg = ks * (K/KS), kend = kbeg + K/KS;

  __shared__ __align__(16) char smem[48*1024];
  char* As = smem;            // 128 rows x 128B (64 bf16)
  char* Bs = smem + 16*1024;  // 128 rows x 256B (64 fp32)

  const int tid = threadIdx.x, lane = tid & 63, w = tid >> 6;
  const int wr = w >> 1, wc = w & 1;

  const unsigned short* asrc[4];
  #pragma unroll
  for (int i = 0; i < 4; ++i){
    int C = (i*4 + w)*64 + lane;
    int row = C >> 3, cc = C & 7;
    int sc = cc ^ (row & 7);
    int lr = by*128 + row; if (lr >= Me) lr = Me-1;
    int li = rbase + lr;
    int ar = GATHER ? (tok_list[li] >> 1) : li;
    asrc[i] = A + (long long)ar * lda + sc*8;
  }
  const float* bsrc[8];
  #pragma unroll
  for (int i = 0; i < 8; ++i){
    int C = (i*4 + w)*64 + lane;
    int row = C >> 4, cc = C & 15;
    int sc = cc ^ (row & 7);
    bsrc[i] = B + (long long)(bx*128 + row) * ldb + sc*4;
  }

  f32x4 acc[4][4] = {};

  for (int k0 = kbeg; k0 < kend; k0 += 64){
    __syncthreads();
    #pragma unroll
    for (int i = 0; i < 4; ++i) gload16(asrc[i] + k0, As + (i*4 + w)*1024);
    #pragma unroll
    for (int i = 0; i < 8; ++i) gload16(bsrc[i] + k0, Bs + (i*4 + w)*1024);
    __syncthreads();
    #pragma unroll
    for (int kk=0;kk<2;++kk){
      bf16x8 af[4], bfr[4];
      #pragma unroll
      for (int m=0;m<4;++m){
        int R = wr*64 + m*16 + (lane&15);
        int ca = (kk*4 + (lane>>4)) ^ (R&7);
        af[m] = *(const bf16x8*)(As + R*128 + ca*16);
      }
      #pragma unroll
      for (int n=0;n<4;++n){
        int R = wc*64 + n*16 + (lane&15);
        int cb = kk*8 + (lane>>4)*2;
        f32x4 v0 = *(const f32x4*)(Bs + R*256 + ((cb  )^(R&7))*16);
        f32x4 v1 = *(const f32x4*)(Bs + R*256 + ((cb+1)^(R&7))*16);
        bf16x8 t;
        t[0]=(__bf16)v0[0]; t[1]=(__bf16)v0[1]; t[2]=(__bf16)v0[2]; t[3]=(__bf16)v0[3];
        t[4]=(__bf16)v1[0]; t[5]=(__bf16)v1[1]; t[6]=(__bf16)v1[2]; t[7]=(__bf16)v1[3];
        bfr[n] = t;
      }
      #pragma unroll
      for (int m=0;m<4;++m)
        #pragma unroll
        for (int n=0;n<4;++n)
          acc[m][n] = __builtin_amdgcn_mfma_f32_16x16x32_bf16(af[m], bfr[n], acc[m][n], 0, 0, 0);
    }
  }

  #pragma unroll
  for (int m=0;m<4;++m){
    #pragma unroll
    for (int r=0;r<4;++r){
      int lr = by*128 + wr*64 + m*16 + 4*(lane>>4) + r;
      if (lr >= Me) continue;
      #pragma unroll
      for (int n=0;n<4;++n){
        int col = bx*128 + wc*64 + n*16 + (lane&15);
        float v = acc[m][n][r];
        if constexpr (EPI == 1){
          if (ks == 0) v += resid[(long long)lr*ldc + col];
          Cf[ks*ksoff + (long long)lr*ldc + col] = v;
        } else if constexpr (EPI == 2){
          float g = 0.5f * v * (1.0f + erff(v * 0.70710678118654752f));
          Cb[(long long)(rbase+lr)*ldc + col] = f2bf(g);
        } else if constexpr (EPI == 3){
          int gi = rbase + lr;
          int ts = tok_list[gi];
          Cf[ks*ksoff + (long long)ts*ldc + col] = v * wgt[gi];
        } else {
          Cb[(long long)lr*ldc + col] = f2bf(v);
        }
      }
    }
  }
}

// ---------------- RoPE on bf16 qkv; q,k out bf16 [t][h][64] ----------------
__global__ __launch_bounds__(256) void rope_kernel(const unsigned short* __restrict__ qkvb,
    unsigned short* __restrict__ q, unsigned short* __restrict__ k){
  int t = blockIdx.x, tid = threadIdx.x;
  const unsigned short* row = qkvb + (long long)t*3072;
  #pragma unroll
  for (int u2=0; u2<2; ++u2){
    int pid = tid + u2*256;
    int hh = pid >> 5, j = pid & 31;
    float invf = __expf(-(float)j * 0.28782313662425575f);
    float fr = (float)t * invf;
    float sn, cs;
    __sincosf(fr, &sn, &cs);
    int base = hh*64 + j;
    long long ob_ = (long long)t*1024 + base;
    float a = bf2f(row[base]), b = bf2f(row[base+32]);
    q[ob_]    = f2bf(a*cs - b*sn);
    q[ob_+32] = f2bf(b*cs + a*sn);
    a = bf2f(row[1024+base]); b = bf2f(row[1024+base+32]);
    k[ob_]    = f2bf(a*cs - b*sn);
    k[ob_+32] = f2bf(b*cs + a*sn);
  }
}

// ---------------- causal flash attention ----------------
__global__ __launch_bounds__(256) void attn_kernel(
    const unsigned short* __restrict__ Q,
    const unsigned short* __restrict__ K,
    const unsigned short* __restrict__ V, int ldv,
    unsigned short* __restrict__ O)
{
  const int bx = blockIdx.x, h = blockIdx.y;
  const int q0 = bx*64;
  const int tid = threadIdx.x, lane = tid&63, w = tid>>6;

  __shared__ __align__(16) unsigned short Ks[64*64];
  __shared__ __align__(16) unsigned short Vs[64*64];
  __shared__ __align__(16) unsigned short Ps[4*16*64];
  unsigned short* Pw = Ps + w*1024;

  const int qrow = q0 + w*16 + (lane&15);
  bf16x8 aq[2];
  #pragma unroll
  for (int kk=0;kk<2;++kk)
    aq[kk] = *(const bf16x8*)&Q[(long long)qrow*1024 + h*64 + 32*kk + 8*(lane>>4)];

  f32x4 o[4] = {};
  float Mx[4] = {-INFINITY,-INFINITY,-INFINITY,-INFINITY};
  float Ls[4] = {0.f,0.f,0.f,0.f};

  const int row_g = q0 + w*16 + 4*(lane>>4);
  const int nt = bx + 1;
  for (int it = 0; it < nt; ++it){
    int k0 = it*64;
    #pragma unroll
    for (int i=0;i<2;++i){
      int seg = 4*i + w;
      int row = seg*8 + (lane>>3);
      int cs = (lane&7) ^ (row&7);
      gload16(&K[(long long)(k0+row)*1024 + h*64 + cs*8], &Ks[seg*512]);
      gload16(&V[(long long)(k0+row)*ldv  + h*64 + cs*8], &Vs[seg*512]);
    }
    __syncthreads();
    f32x4 st[4];
    #pragma unroll
    for (int kt=0;kt<4;++kt){
      f32x4 s = {0.f,0.f,0.f,0.f};
      #pragma unroll
      for (int kk=0;kk<2;++kk){
        int R = kt*16 + (lane&15);
        int ch = ((lane>>4)+4*kk) ^ (R&7);
        bf16x8 bk = *(const bf16x8*)&Ks[R*64 + ch*8];
        s = __builtin_amdgcn_mfma_f32_16x16x32_bf16(aq[kk], bk, s, 0,0,0);
      }
      st[kt] = s;
    }
    #pragma unroll
    for (int kt=0;kt<4;++kt){
      int col = k0 + kt*16 + (lane&15);
      #pragma unroll
      for (int r=0;r<4;++r){
        float vv = st[kt][r]*0.125f;
        st[kt][r] = (col <= row_g + r) ? vv : -INFINITY;
      }
    }
    float sf[4];
    #pragma unroll
    for (int r=0;r<4;++r){
      float mx = fmaxf(fmaxf(st[0][r],st[1][r]),fmaxf(st[2][r],st[3][r]));
      mx = fmaxf(mx, __shfl_xor(mx,1));
      mx = fmaxf(mx, __shfl_xor(mx,2));
      mx = fmaxf(mx, __shfl_xor(mx,4));
      mx = fmaxf(mx, __shfl_xor(mx,8));
      float mn = fmaxf(Mx[r], mx);
      float sc = __expf(Mx[r]-mn);
      Mx[r]=mn; sf[r]=sc;
      float ls=0.f;
      #pragma unroll
      for (int kt=0;kt<4;++kt){ float pp = __expf(st[kt][r]-mn); st[kt][r]=pp; ls+=pp; }
      Ls[r] = Ls[r]*sc + ls;
    }
    #pragma unroll
    for (int dt=0;dt<4;++dt)
      #pragma unroll
      for (int r=0;r<4;++r) o[dt][r] *= sf[r];
    #pragma unroll
    for (int kt=0;kt<4;++kt)
      #pragma unroll
      for (int r=0;r<4;++r){
        int prow = 4*(lane>>4)+r, pcol = kt*16+(lane&15);
        int byteoff = (prow*128 + pcol*2) ^ ((prow&7)<<4);
        *(unsigned short*)((char*)Pw + byteoff) = f2bf(st[kt][r]);
      }
    bf16x8 pa[2];
    #pragma unroll
    for (int kk=0;kk<2;++kk){
      int pr = lane&15;
      int ch = ((lane>>4)+4*kk) ^ (pr&7);
      pa[kk] = *(const bf16x8*)&Pw[pr*64 + ch*8];
    }
    #pragma unroll
    for (int dt=0;dt<4;++dt){
      #pragma unroll
      for (int kk=0;kk<2;++kk){
        union { unsigned short u[8]; bf16x8 v; } Ub;
        #pragma unroll
        for (int j=0;j<8;++j){
          int kr = 32*kk + 8*(lane>>4) + j;
          int d = dt*16 + (lane&15);
          int byteoff = (kr*128 + d*2) ^ ((kr&7)<<4);
          Ub.u[j] = *(const unsigned short*)((const char*)Vs + byteoff);
        }
        o[dt] = __builtin_amdgcn_mfma_f32_16x16x32_bf16(pa[kk], Ub.v, o[dt], 0,0,0);
      }
    }
    __syncthreads();
  }
  #pragma unroll
  for (int r=0;r<4;++r){
    float l = Ls[r];
    l += __shfl_xor(l,1); l += __shfl_xor(l,2); l += __shfl_xor(l,4); l += __shfl_xor(l,8);
    Ls[r] = 1.0f / l;
  }
  #pragma unroll
  for (int dt=0;dt<4;++dt)
    #pragma unroll
    for (int r=0;r<4;++r){
      float vv = o[dt][r]*Ls[r];
      int rg = row_g + r;
      O[(long long)rg*1024 + h*64 + dt*16 + (lane&15)] = f2bf(vv);
    }
}

// ---------------- router + top2 ----------------
__global__ __launch_bounds__(256) void router_kernel(const float* __restrict__ h2f, const float* __restrict__ rw,
    float* __restrict__ probs, int* __restrict__ tope, float* __restrict__ topw, int* __restrict__ counts){
  int t = blockIdx.x, tid = threadIdx.x;
  float4 hv = *(const float4*)(h2f + (long long)t*1024 + tid*4);
  float pe[8];
  #pragma unroll
  for (int e2=0;e2<8;++e2){
    float4 wv = *(const float4*)(rw + e2*1024 + tid*4);
    pe[e2] = hv.x*wv.x + hv.y*wv.y + hv.z*wv.z + hv.w*wv.w;
  }
  __shared__ float lds[32];
  #pragma unroll
  for (int e2=0;e2<8;++e2){
    float v = pe[e2];
    for (int m=32;m;m>>=1) v += __shfl_xor(v,m);
    if ((tid&63)==0) lds[(tid>>6)*8+e2] = v;
  }
  __syncthreads();
  if (tid==0){
    float lg[8], pp[8];
    #pragma unroll
    for (int e2=0;e2<8;++e2) lg[e2] = lds[e2]+lds[8+e2]+lds[16+e2]+lds[24+e2];
    float mx = lg[0];
    for (int e2=1;e2<8;++e2) mx = fmaxf(mx, lg[e2]);
    float s = 0.f;
    for (int e2=0;e2<8;++e2){ pp[e2] = __expf(lg[e2]-mx); s += pp[e2]; }
    float inv = 1.0f/s;
    int i0 = 0;
    for (int e2=1;e2<8;++e2) if (pp[e2] > pp[i0]) i0 = e2;
    int i1 = (i0==0)?1:0;
    for (int e2=0;e2<8;++e2) if (e2!=i0 && pp[e2] > pp[i1]) i1 = e2;
    for (int e2=0;e2<8;++e2) probs[t*8+e2] = pp[e2]*inv;
    float p0 = pp[i0], p1 = pp[i1], wsum = p0+p1;
    tope[t*2] = i0; tope[t*2+1] = i1;
    topw[t*2] = p0/wsum; topw[t*2+1] = p1/wsum;
    atomicAdd(&counts[i0],1); atomicAdd(&counts[i1],1);
  }
}

__global__ void init_kernel(int* counts, int* cursor){
  int i = threadIdx.x;
  if (i<8){ counts[i]=0; cursor[i]=0; }
}

__global__ void prefix_kernel(const int* counts, int* offs){
  if (threadIdx.x==0){
    int a=0;
    for (int e2=0;e2<8;++e2){ offs[e2]=a; a+=counts[e2]; }
  }
}

__global__ void scatter_kernel(const int* __restrict__ tope, const float* __restrict__ topw,
    const int* __restrict__ offs, int* __restrict__ cursor, int* __restrict__ tok_list, float* __restrict__ wgt){
  int t = blockIdx.x*blockDim.x + threadIdx.x;
  if (t >= 2048) return;
  #pragma unroll
  for (int s=0;s<2;++s){
    int e2 = tope[t*2+s];
    int pos = atomicAdd(&cursor[e2], 1);
    int i = offs[e2] + pos;
    tok_list[i] = t*2+s;
    wgt[i] = topw[t*2+s];
  }
}

__global__ __launch_bounds__(256) void aux_kernel(const float* __restrict__ probs, float* __restrict__ out){
  int tid = threadIdx.x;
  float pe[8] = {0,0,0,0,0,0,0,0};
  for (int t = tid; t < 2048; t += 256){
    #pragma unroll
    for (int e2=0;e2<8;++e2) pe[e2] += probs[t*8+e2];
  }
  __shared__ float lds[32];
  #pragma unroll
  for (int e2=0;e2<8;++e2){
    float v = pe[e2];
    for (int m=32;m;m>>=1) v += __shfl_xor(v,m);
    if ((tid&63)==0) lds[(tid>>6)*8 + e2] = v;
  }
  __syncthreads();
  if (tid==0){
    float aux = 0.f;
    #pragma unroll
    for (int e2=0;e2<8;++e2){
      float mean = (lds[e2]+lds[8+e2]+lds[16+e2]+lds[24+e2]) * (1.0f/2048.0f);
      aux += mean*mean;
    }
    out[2097152] = 8.0f * aux;
  }
}

__global__ __launch_bounds__(256) void final_kernel(const float* __restrict__ x1, const float* __restrict__ slots, float* __restrict__ out){
  int t = blockIdx.x, tid = threadIdx.x;
  long long b = (long long)t*1024 + tid*4;
  float4 a   = *(const float4*)(x1 + b);
  long long s = (long long)t*2048 + tid*4;
  float4 s00 = *(const float4*)(slots + s);
  float4 s01 = *(const float4*)(slots + s + 1024);
  float4 s10 = *(const float4*)(slots + s + 4194304);
  float4 s11 = *(const float4*)(slots + s + 4194304 + 1024);
  float4 rr;
  rr.x = a.x + s00.x + s01.x + s10.x + s11.x;
  rr.y = a.y + s00.y + s01.y + s10.y + s11.y;
  rr.z = a.z + s00.z + s01.z + s10.z + s11.z;
  rr.w = a.w + s00.w + s01.w + s10.w + s11.w;
  *(float4*)(out + b) = rr;
}

extern "C" void kernel_launch(void* const* d_in, const int* in_sizes, int n_in,
                              void* d_out, int out_size, void* d_ws, size_t ws_size,
                              hipStream_t stream)
{
  (void)in_sizes; (void)n_in; (void)out_size; (void)ws_size;
  const float* x    = (const float*)d_in[0];
  const float* qkvw = (const float*)d_in[1];
  const float* outw = (const float*)d_in[2];
  const float* rw   = (const float*)d_in[3];
  const float* w1   = (const float*)d_in[4];
  const float* w2   = (const float*)d_in[5];
  const float* n1w  = (const float*)d_in[6];
  const float* n2w  = (const float*)d_in[7];
  float* out = (float*)d_out;

  char* base = (char*)d_ws;
  const size_t MB = 1ull<<20;
  // region A [0,32MB): pre-MoE bf16 buffers; hid aliases the whole region later
  unsigned short* h_b  = (unsigned short*)(base + 0*MB);    // 4MB
  unsigned short* qb   = (unsigned short*)(base + 4*MB);    // 4MB
  unsigned short* kb   = (unsigned short*)(base + 8*MB);    // 4MB
  unsigned short* ob   = (unsigned short*)(base + 12*MB);   // 4MB
  unsigned short* qkvb = (unsigned short*)(base + 16*MB);   // 12MB
  unsigned short* hid  = (unsigned short*)(base + 0*MB);    // 32MB alias (all above dead by w1)
  // region B [32MB,64MB): out-proj partials + h2f; slots aliases later
  float* x1a   = (float*)(base + 32*MB);                    // 8MB
  float* x1b   = (float*)(base + 40*MB);                    // 8MB
  float* h2f   = (float*)(base + 48*MB);                    // 8MB
  float* slots = (float*)(base + 32*MB);                    // 32MB alias (2 ksplit x 16MB)
  // persistent
  float* x1          = (float*)(base + 64*MB);              // 8MB
  unsigned short* h2b= (unsigned short*)(base + 72*MB);     // 4MB
  float* probs = (float*)(base + 76*MB);
  int*   tope  = (int*)(base + 76*MB + 256*1024);
  float* topw  = (float*)(base + 76*MB + 512*1024);
  int*   tok_list = (int*)(base + 76*MB + 768*1024);
  float* wgt   = (float*)(base + 76*MB + 1024*1024);
  int*   counts= (int*)(base + 78*MB);
  int*   offs  = (int*)(base + 78*MB + 256);
  int*   cursor= (int*)(base + 78*MB + 512);

  init_kernel<<<1,64,0,stream>>>(counts, cursor);
  rmsnorm_kernel<<<2048,256,0,stream>>>(x, n1w, h_b);
  gemm_bt<4,false><<<dim3(24,16,1),256,0,stream>>>(h_b,1024, qkvw,0,1024, 2048,3072,1024, 1,0,
      nullptr,nullptr,nullptr,nullptr,nullptr, nullptr,qkvb,3072);
  rope_kernel<<<2048,256,0,stream>>>(qkvb, qb, kb);
  attn_kernel<<<dim3(32,16),256,0,stream>>>(qb, kb, qkvb+2048, 3072, ob);
  gemm_bt<1,false><<<dim3(8,16,2),256,0,stream>>>(ob,1024, outw,0,1024, 2048,1024,1024, 2,(long long)2048*1024,
      nullptr,nullptr,nullptr,nullptr, x, x1a,nullptr,1024);
  rmsnorm2_kernel<<<2048,256,0,stream>>>(x1a, x1b, n2w, x1, h2b, h2f);
  router_kernel<<<2048,256,0,stream>>>(h2f, rw, probs, tope, topw, counts);
  prefix_kernel<<<1,64,0,stream>>>(counts, offs);
  scatter_kernel<<<8,256,0,stream>>>(tope, topw, offs, cursor, tok_list, wgt);
  gemm_bt<2,true><<<dim3(32,16,8),256,0,stream>>>(h2b,1024, w1,(long long)4096*1024,1024, 2048,4096,1024, 1,0,
      counts,offs,tok_list,nullptr,nullptr, nullptr,hid,4096);
  gemm_bt<3,false><<<dim3(8,16,16),256,0,stream>>>(hid,4096, w2,(long long)4096*1024,4096, 2048,1024,4096, 2,(long long)2048*2048,
      counts,offs,tok_list,wgt,nullptr, slots,nullptr,1024);
  aux_kernel<<<1,256,0,stream>>>(probs, out);
  final_kernel<<<2048,256,0,stream>>>(x1, slots, out);
}

// Round 3
// 452.935 us; speedup vs baseline: 1.3307x; 1.0910x over previous
//
#include <hip/hip_runtime.h>
#include <cstdint>
#include <math.h>

typedef float f32x4 __attribute__((ext_vector_type(4)));
typedef __bf16 bf16x8 __attribute__((ext_vector_type(8)));
typedef unsigned short us4 __attribute__((ext_vector_type(4)));

#define DEV static __device__ __forceinline__

DEV unsigned short f2bf(float f){
  union { __bf16 h; unsigned short u; } cv; cv.h = (__bf16)f; return cv.u;
}
DEV float bf2f(unsigned short u){ return __uint_as_float((unsigned int)u << 16); }

DEV void gload16(const void* g, void* l){
  __builtin_amdgcn_global_load_lds((__attribute__((address_space(1))) void*)g,
                                   (__attribute__((address_space(3))) void*)l, 16, 0, 0);
}

// ---------------- RMSNorm 1 ----------------
__global__ __launch_bounds__(256) void rmsnorm_kernel(const float* __restrict__ x, const float* __restrict__ w,
    unsigned short* __restrict__ ob){
  int t = blockIdx.x, tid = threadIdx.x;
  float4 xv = *(const float4*)(x + (long long)t*1024 + tid*4);
  float ss = xv.x*xv.x + xv.y*xv.y + xv.z*xv.z + xv.w*xv.w;
  for (int m=32;m;m>>=1) ss += __shfl_xor(ss,m);
  __shared__ float lds[4];
  if ((tid&63)==0) lds[tid>>6] = ss;
  __syncthreads();
  float tot = lds[0]+lds[1]+lds[2]+lds[3];
  float inv = rsqrtf(tot*(1.0f/1024.0f) + 1.1920928955078125e-07f);
  float4 wv = *(const float4*)(w + tid*4);
  us4 rb = { f2bf(xv.x*inv*wv.x), f2bf(xv.y*inv*wv.y), f2bf(xv.z*inv*wv.z), f2bf(xv.w*inv*wv.w) };
  *(us4*)&ob[(long long)t*1024 + tid*4] = rb;
}

// ---------------- RMSNorm 2: sum KS partials, write x1 fp32 + h2 bf16 + h2 fp32 ----------------
__global__ __launch_bounds__(256) void rmsnorm2_kernel(const float* __restrict__ xp, int ksn, long long kstride,
    const float* __restrict__ w, float* __restrict__ x1, unsigned short* __restrict__ hb, float* __restrict__ hf){
  int t = blockIdx.x, tid = threadIdx.x;
  long long b = (long long)t*1024 + tid*4;
  float4 xv = {0.f,0.f,0.f,0.f};
  for (int ks=0; ks<ksn; ++ks){
    float4 a = *(const float4*)(xp + ks*kstride + b);
    xv.x+=a.x; xv.y+=a.y; xv.z+=a.z; xv.w+=a.w;
  }
  *(float4*)(x1 + b) = xv;
  float ss = xv.x*xv.x + xv.y*xv.y + xv.z*xv.z + xv.w*xv.w;
  for (int m=32;m;m>>=1) ss += __shfl_xor(ss,m);
  __shared__ float lds[4];
  if ((tid&63)==0) lds[tid>>6] = ss;
  __syncthreads();
  float tot = lds[0]+lds[1]+lds[2]+lds[3];
  float inv = rsqrtf(tot*(1.0f/1024.0f) + 1.1920928955078125e-07f);
  float4 wv = *(const float4*)(w + tid*4);
  float r0 = xv.x*inv*wv.x, r1 = xv.y*inv*wv.y, r2 = xv.z*inv*wv.z, r3 = xv.w*inv*wv.w;
  us4 rb = { f2bf(r0), f2bf(r1), f2bf(r2), f2bf(r3) };
  *(us4*)&hb[b] = rb;
  float4 rf; rf.x=r0; rf.y=r1; rf.z=r2; rf.w=r3;
  *(float4*)(hf + b) = rf;
}

// ---------------- generic GEMM  C[M,N] = A[M,K](bf16) * B[N,K]^T(fp32) ----------------
// BK=32, double-buffered LDS (2 x 24KB), prefetch pipeline:
//   stage(buf0); barrier; { stage(next); compute(cur); barrier; }
// A rows 64B, swizzle c ^ ((R>>1)&3); B rows 128B fp32, swizzle c ^ (R&7).
// EPI: 1 = fp32 (+resid if ks==0) to Cf+ks*ksoff, 2 = gelu->bf16 Cb rows rbase+lr,
//      3 = fp32 acc*wgt scattered to Cf+ks*ksoff+tok_slot*ldc, 4 = plain bf16 to Cb
template<int EPI, bool GATHER>
__global__ __launch_bounds__(256) void gemm_bt(
    const unsigned short* __restrict__ A, int lda,
    const float* __restrict__ Bw, long long bstride, int ldb,
    int M, int N, int K, int KS, long long ksoff,
    const int* __restrict__ counts, const int* __restrict__ offs,
    const int* __restrict__ tok_list, const float* __restrict__ wgt,
    const float* __restrict__ resid,
    float* __restrict__ Cf, unsigned short* __restrict__ Cb, int ldc)
{
  const int z = blockIdx.z;
  const int e = z / KS, ks = z - e*KS;
  const int Me = counts ? counts[e] : M;
  const int by = blockIdx.y;
  if (by * 128 >= Me) return;
  const int rbase = offs ? offs[e] : 0;
  const int bx = blockIdx.x;
  const float* B = Bw + (long long)e * bstride;
  const int kn = K / KS;
  const int kbeg = ks * kn;
  const int nt = kn >> 5;

  __shared__ __align__(16) char smem[49152]; // 2 x (A 8KB + B 16KB)

  const int tid = threadIdx.x, lane = tid & 63, w = tid >> 6;
  const int wr = w >> 1, wc = w & 1;

  const unsigned short* asrc[2];
  #pragma unroll
  for (int i = 0; i < 2; ++i){
    int G = tid + i*256;
    int R = G >> 2, c = G & 3;
    int cg = c ^ ((R>>1)&3);
    int lr = by*128 + R; if (lr >= Me) lr = Me-1;
    int li = rbase + lr;
    int ar = GATHER ? (tok_list[li] >> 1) : li;
    asrc[i] = A + (long long)ar * lda + kbeg + cg*8;
  }
  const float* bsrc[4];
  #pragma unroll
  for (int i = 0; i < 4; ++i){
    int G = tid + i*256;
    int R = G >> 3, c = G & 7;
    int cg = c ^ (R & 7);
    bsrc[i] = B + (long long)(bx*128 + R) * ldb + kbeg + cg*4;
  }

  f32x4 acc[4][4] = {};

  auto stage = [&](int b, int kof){
    char* s = smem + b*24576;
    #pragma unroll
    for (int i = 0; i < 2; ++i) gload16(asrc[i] + kof, s + (i*256 + w*64)*16);
    #pragma unroll
    for (int i = 0; i < 4; ++i) gload16(bsrc[i] + kof, s + 8192 + (i*256 + w*64)*16);
  };

  stage(0, 0);
  __syncthreads();

  for (int t = 0; t < nt; ++t){
    int cur = t & 1;
    if (t + 1 < nt) stage(cur ^ 1, (t+1)*32);
    const char* abase = smem + cur*24576;
    const char* bbase = abase + 8192;
    bf16x8 af[4], bfr[4];
    #pragma unroll
    for (int m=0;m<4;++m){
      int R = wr*64 + m*16 + (lane&15);
      int c = (lane>>4) ^ ((R>>1)&3);
      af[m] = *(const bf16x8*)(abase + R*64 + c*16);
    }
    #pragma unroll
    for (int n=0;n<4;++n){
      int R = wc*64 + n*16 + (lane&15);
      int c0 = ((lane>>4)*2) ^ (R&7);
      int c1 = c0 ^ 1;
      f32x4 v0 = *(const f32x4*)(bbase + R*128 + c0*16);
      f32x4 v1 = *(const f32x4*)(bbase + R*128 + c1*16);
      bf16x8 tt;
      tt[0]=(__bf16)v0[0]; tt[1]=(__bf16)v0[1]; tt[2]=(__bf16)v0[2]; tt[3]=(__bf16)v0[3];
      tt[4]=(__bf16)v1[0]; tt[5]=(__bf16)v1[1]; tt[6]=(__bf16)v1[2]; tt[7]=(__bf16)v1[3];
      bfr[n] = tt;
    }
    #pragma unroll
    for (int m=0;m<4;++m)
      #pragma unroll
      for (int n=0;n<4;++n)
        acc[m][n] = __builtin_amdgcn_mfma_f32_16x16x32_bf16(af[m], bfr[n], acc[m][n], 0, 0, 0);
    __syncthreads();
  }

  #pragma unroll
  for (int m=0;m<4;++m){
    #pragma unroll
    for (int r=0;r<4;++r){
      int lr = by*128 + wr*64 + m*16 + 4*(lane>>4) + r;
      if (lr >= Me) continue;
      #pragma unroll
      for (int n=0;n<4;++n){
        int col = bx*128 + wc*64 + n*16 + (lane&15);
        float v = acc[m][n][r];
        if constexpr (EPI == 1){
          if (ks == 0) v += resid[(long long)lr*ldc + col];
          Cf[ks*ksoff + (long long)lr*ldc + col] = v;
        } else if constexpr (EPI == 2){
          float g = 0.5f * v * (1.0f + erff(v * 0.70710678118654752f));
          Cb[(long long)(rbase+lr)*ldc + col] = f2bf(g);
        } else if constexpr (EPI == 3){
          int gi = rbase + lr;
          int ts = tok_list[gi];
          Cf[ks*ksoff + (long long)ts*ldc + col] = v * wgt[gi];
        } else {
          Cb[(long long)lr*ldc + col] = f2bf(v);
        }
      }
    }
  }
}

// ---------------- RoPE on bf16 qkv; q,k out bf16 [t][h][64] ----------------
__global__ __launch_bounds__(256) void rope_kernel(const unsigned short* __restrict__ qkvb,
    unsigned short* __restrict__ q, unsigned short* __restrict__ k){
  int t = blockIdx.x, tid = threadIdx.x;
  const unsigned short* row = qkvb + (long long)t*3072;
  #pragma unroll
  for (int u2=0; u2<2; ++u2){
    int pid = tid + u2*256;
    int hh = pid >> 5, j = pid & 31;
    float invf = __expf(-(float)j * 0.28782313662425575f);
    float fr = (float)t * invf;
    float sn, cs;
    __sincosf(fr, &sn, &cs);
    int base = hh*64 + j;
    long long ob_ = (long long)t*1024 + base;
    float a = bf2f(row[base]), b = bf2f(row[base+32]);
    q[ob_]    = f2bf(a*cs - b*sn);
    q[ob_+32] = f2bf(b*cs + a*sn);
    a = bf2f(row[1024+base]); b = bf2f(row[1024+base+32]);
    k[ob_]    = f2bf(a*cs - b*sn);
    k[ob_+32] = f2bf(b*cs + a*sn);
  }
}

// ---------------- causal flash attention ----------------
__global__ __launch_bounds__(256) void attn_kernel(
    const unsigned short* __restrict__ Q,
    const unsigned short* __restrict__ K,
    const unsigned short* __restrict__ V, int ldv,
    unsigned short* __restrict__ O)
{
  const int bx = blockIdx.x, h = blockIdx.y;
  const int q0 = bx*64;
  const int tid = threadIdx.x, lane = tid&63, w = tid>>6;

  __shared__ __align__(16) unsigned short Ks[64*64];
  __shared__ __align__(16) unsigned short Vs[64*64];
  __shared__ __align__(16) unsigned short Ps[4*16*64];
  unsigned short* Pw = Ps + w*1024;

  const int qrow = q0 + w*16 + (lane&15);
  bf16x8 aq[2];
  #pragma unroll
  for (int kk=0;kk<2;++kk)
    aq[kk] = *(const bf16x8*)&Q[(long long)qrow*1024 + h*64 + 32*kk + 8*(lane>>4)];

  f32x4 o[4] = {};
  float Mx[4] = {-INFINITY,-INFINITY,-INFINITY,-INFINITY};
  float Ls[4] = {0.f,0.f,0.f,0.f};

  const int row_g = q0 + w*16 + 4*(lane>>4);
  const int nt = bx + 1;
  for (int it = 0; it < nt; ++it){
    int k0 = it*64;
    #pragma unroll
    for (int i=0;i<2;++i){
      int seg = 4*i + w;
      int row = seg*8 + (lane>>3);
      int cs = (lane&7) ^ (row&7);
      gload16(&K[(long long)(k0+row)*1024 + h*64 + cs*8], &Ks[seg*512]);
      gload16(&V[(long long)(k0+row)*ldv  + h*64 + cs*8], &Vs[seg*512]);
    }
    __syncthreads();
    f32x4 st[4];
    #pragma unroll
    for (int kt=0;kt<4;++kt){
      f32x4 s = {0.f,0.f,0.f,0.f};
      #pragma unroll
      for (int kk=0;kk<2;++kk){
        int R = kt*16 + (lane&15);
        int ch = ((lane>>4)+4*kk) ^ (R&7);
        bf16x8 bk = *(const bf16x8*)&Ks[R*64 + ch*8];
        s = __builtin_amdgcn_mfma_f32_16x16x32_bf16(aq[kk], bk, s, 0,0,0);
      }
      st[kt] = s;
    }
    #pragma unroll
    for (int kt=0;kt<4;++kt){
      int col = k0 + kt*16 + (lane&15);
      #pragma unroll
      for (int r=0;r<4;++r){
        float vv = st[kt][r]*0.125f;
        st[kt][r] = (col <= row_g + r) ? vv : -INFINITY;
      }
    }
    float sf[4];
    #pragma unroll
    for (int r=0;r<4;++r){
      float mx = fmaxf(fmaxf(st[0][r],st[1][r]),fmaxf(st[2][r],st[3][r]));
      mx = fmaxf(mx, __shfl_xor(mx,1));
      mx = fmaxf(mx, __shfl_xor(mx,2));
      mx = fmaxf(mx, __shfl_xor(mx,4));
      mx = fmaxf(mx, __shfl_xor(mx,8));
      float mn = fmaxf(Mx[r], mx);
      float sc = __expf(Mx[r]-mn);
      Mx[r]=mn; sf[r]=sc;
      float ls=0.f;
      #pragma unroll
      for (int kt=0;kt<4;++kt){ float pp = __expf(st[kt][r]-mn); st[kt][r]=pp; ls+=pp; }
      Ls[r] = Ls[r]*sc + ls;
    }
    #pragma unroll
    for (int dt=0;dt<4;++dt)
      #pragma unroll
      for (int r=0;r<4;++r) o[dt][r] *= sf[r];
    #pragma unroll
    for (int kt=0;kt<4;++kt)
      #pragma unroll
      for (int r=0;r<4;++r){
        int prow = 4*(lane>>4)+r, pcol = kt*16+(lane&15);
        int byteoff = (prow*128 + pcol*2) ^ ((prow&7)<<4);
        *(unsigned short*)((char*)Pw + byteoff) = f2bf(st[kt][r]);
      }
    bf16x8 pa[2];
    #pragma unroll
    for (int kk=0;kk<2;++kk){
      int pr = lane&15;
      int ch = ((lane>>4)+4*kk) ^ (pr&7);
      pa[kk] = *(const bf16x8*)&Pw[pr*64 + ch*8];
    }
    #pragma unroll
    for (int dt=0;dt<4;++dt){
      #pragma unroll
      for (int kk=0;kk<2;++kk){
        union { unsigned short u[8]; bf16x8 v; } Ub;
        #pragma unroll
        for (int j=0;j<8;++j){
          int kr = 32*kk + 8*(lane>>4) + j;
          int d = dt*16 + (lane&15);
          int byteoff = (kr*128 + d*2) ^ ((kr&7)<<4);
          Ub.u[j] = *(const unsigned short*)((const char*)Vs + byteoff);
        }
        o[dt] = __builtin_amdgcn_mfma_f32_16x16x32_bf16(pa[kk], Ub.v, o[dt], 0,0,0);
      }
    }
    __syncthreads();
  }
  #pragma unroll
  for (int r=0;r<4;++r){
    float l = Ls[r];
    l += __shfl_xor(l,1); l += __shfl_xor(l,2); l += __shfl_xor(l,4); l += __shfl_xor(l,8);
    Ls[r] = 1.0f / l;
  }
  #pragma unroll
  for (int dt=0;dt<4;++dt)
    #pragma unroll
    for (int r=0;r<4;++r){
      float vv = o[dt][r]*Ls[r];
      int rg = row_g + r;
      O[(long long)rg*1024 + h*64 + dt*16 + (lane&15)] = f2bf(vv);
    }
}

// ---------------- router + top2 ----------------
__global__ __launch_bounds__(256) void router_kernel(const float* __restrict__ h2f, const float* __restrict__ rw,
    float* __restrict__ probs, int* __restrict__ tope, float* __restrict__ topw, int* __restrict__ counts){
  int t = blockIdx.x, tid = threadIdx.x;
  float4 hv = *(const float4*)(h2f + (long long)t*1024 + tid*4);
  float pe[8];
  #pragma unroll
  for (int e2=0;e2<8;++e2){
    float4 wv = *(const float4*)(rw + e2*1024 + tid*4);
    pe[e2] = hv.x*wv.x + hv.y*wv.y + hv.z*wv.z + hv.w*wv.w;
  }
  __shared__ float lds[32];
  #pragma unroll
  for (int e2=0;e2<8;++e2){
    float v = pe[e2];
    for (int m=32;m;m>>=1) v += __shfl_xor(v,m);
    if ((tid&63)==0) lds[(tid>>6)*8+e2] = v;
  }
  __syncthreads();
  if (tid==0){
    float lg[8], pp[8];
    #pragma unroll
    for (int e2=0;e2<8;++e2) lg[e2] = lds[e2]+lds[8+e2]+lds[16+e2]+lds[24+e2];
    float mx = lg[0];
    for (int e2=1;e2<8;++e2) mx = fmaxf(mx, lg[e2]);
    float s = 0.f;
    for (int e2=0;e2<8;++e2){ pp[e2] = __expf(lg[e2]-mx); s += pp[e2]; }
    float inv = 1.0f/s;
    int i0 = 0;
    for (int e2=1;e2<8;++e2) if (pp[e2] > pp[i0]) i0 = e2;
    int i1 = (i0==0)?1:0;
    for (int e2=0;e2<8;++e2) if (e2!=i0 && pp[e2] > pp[i1]) i1 = e2;
    for (int e2=0;e2<8;++e2) probs[t*8+e2] = pp[e2]*inv;
    float p0 = pp[i0], p1 = pp[i1], wsum = p0+p1;
    tope[t*2] = i0; tope[t*2+1] = i1;
    topw[t*2] = p0/wsum; topw[t*2+1] = p1/wsum;
    atomicAdd(&counts[i0],1); atomicAdd(&counts[i1],1);
  }
}

__global__ void init_kernel(int* counts, int* cursor){
  int i = threadIdx.x;
  if (i<8){ counts[i]=0; cursor[i]=0; }
}

__global__ void prefix_kernel(const int* counts, int* offs){
  if (threadIdx.x==0){
    int a=0;
    for (int e2=0;e2<8;++e2){ offs[e2]=a; a+=counts[e2]; }
  }
}

__global__ void scatter_kernel(const int* __restrict__ tope, const float* __restrict__ topw,
    const int* __restrict__ offs, int* __restrict__ cursor, int* __restrict__ tok_list, float* __restrict__ wgt){
  int t = blockIdx.x*blockDim.x + threadIdx.x;
  if (t >= 2048) return;
  #pragma unroll
  for (int s=0;s<2;++s){
    int e2 = tope[t*2+s];
    int pos = atomicAdd(&cursor[e2], 1);
    int i = offs[e2] + pos;
    tok_list[i] = t*2+s;
    wgt[i] = topw[t*2+s];
  }
}

__global__ __launch_bounds__(256) void aux_kernel(const float* __restrict__ probs, float* __restrict__ out){
  int tid = threadIdx.x;
  float pe[8] = {0,0,0,0,0,0,0,0};
  for (int t = tid; t < 2048; t += 256){
    #pragma unroll
    for (int e2=0;e2<8;++e2) pe[e2] += probs[t*8+e2];
  }
  __shared__ float lds[32];
  #pragma unroll
  for (int e2=0;e2<8;++e2){
    float v = pe[e2];
    for (int m=32;m;m>>=1) v += __shfl_xor(v,m);
    if ((tid&63)==0) lds[(tid>>6)*8 + e2] = v;
  }
  __syncthreads();
  if (tid==0){
    float aux = 0.f;
    #pragma unroll
    for (int e2=0;e2<8;++e2){
      float mean = (lds[e2]+lds[8+e2]+lds[16+e2]+lds[24+e2]) * (1.0f/2048.0f);
      aux += mean*mean;
    }
    out[2097152] = 8.0f * aux;
  }
}

__global__ __launch_bounds__(256) void final_kernel(const float* __restrict__ x1, const float* __restrict__ slots,
    int ksn, long long kstride, float* __restrict__ out){
  int t = blockIdx.x, tid = threadIdx.x;
  long long b = (long long)t*1024 + tid*4;
  float4 a = *(const float4*)(x1 + b);
  long long s = (long long)t*2048 + tid*4;
  for (int ks=0; ks<ksn; ++ks){
    float4 s0 = *(const float4*)(slots + ks*kstride + s);
    float4 s1 = *(const float4*)(slots + ks*kstride + s + 1024);
    a.x += s0.x + s1.x; a.y += s0.y + s1.y; a.z += s0.z + s1.z; a.w += s0.w + s1.w;
  }
  *(float4*)(out + b) = a;
}

extern "C" void kernel_launch(void* const* d_in, const int* in_sizes, int n_in,
                              void* d_out, int out_size, void* d_ws, size_t ws_size,
                              hipStream_t stream)
{
  (void)in_sizes; (void)n_in; (void)out_size;
  const float* x    = (const float*)d_in[0];
  const float* qkvw = (const float*)d_in[1];
  const float* outw = (const float*)d_in[2];
  const float* rw   = (const float*)d_in[3];
  const float* w1   = (const float*)d_in[4];
  const float* w2   = (const float*)d_in[5];
  const float* n1w  = (const float*)d_in[6];
  const float* n2w  = (const float*)d_in[7];
  float* out = (float*)d_out;

  char* base = (char*)d_ws;
  const size_t MB = 1ull<<20;
  const bool big = ws_size >= 150*MB;
  const int KSO = big ? 4 : 2;   // out-proj split-K
  const int KSW = big ? 4 : 2;   // w2 split-K

  // region A [0,32MB): pre-MoE bf16 buffers; hid aliases the whole region later
  unsigned short* h_b  = (unsigned short*)(base + 0*MB);
  unsigned short* qb   = (unsigned short*)(base + 4*MB);
  unsigned short* kb   = (unsigned short*)(base + 8*MB);
  unsigned short* ob   = (unsigned short*)(base + 12*MB);
  unsigned short* qkvb = (unsigned short*)(base + 16*MB);   // 12MB
  unsigned short* hid  = (unsigned short*)(base + 0*MB);    // 32MB alias

  float *x1p, *h2f, *slots, *x1;
  unsigned short* h2b;
  char* small_;
  if (big){
    x1p   = (float*)(base + 32*MB);    // KSO x 8MB  -> [32,64)
    h2f   = (float*)(base + 64*MB);    // 8MB        -> [64,72)
    slots = (float*)(base + 72*MB);    // KSW x 16MB -> [72,136)
    x1    = (float*)(base + 136*MB);   // 8MB
    h2b   = (unsigned short*)(base + 144*MB); // 4MB
    small_ = base + 148*MB;
  } else {
    x1p   = (float*)(base + 32*MB);    // 2 x 8MB    -> [32,48)
    h2f   = (float*)(base + 48*MB);    // 8MB        -> [48,56)
    slots = (float*)(base + 32*MB);    // alias, 2x16MB -> [32,64) (x1p/h2f dead by then)
    x1    = (float*)(base + 64*MB);
    h2b   = (unsigned short*)(base + 72*MB);
    small_ = base + 76*MB;
  }
  float* probs = (float*)(small_);
  int*   tope  = (int*)(small_ + 256*1024);
  float* topw  = (float*)(small_ + 512*1024);
  int*   tok_list = (int*)(small_ + 768*1024);
  float* wgt   = (float*)(small_ + 1024*1024);
  int*   counts= (int*)(small_ + 1536*1024);
  int*   offs  = (int*)(small_ + 1536*1024 + 256);
  int*   cursor= (int*)(small_ + 1536*1024 + 512);

  init_kernel<<<1,64,0,stream>>>(counts, cursor);
  rmsnorm_kernel<<<2048,256,0,stream>>>(x, n1w, h_b);
  gemm_bt<4,false><<<dim3(24,16,1),256,0,stream>>>(h_b,1024, qkvw,0,1024, 2048,3072,1024, 1,0,
      nullptr,nullptr,nullptr,nullptr,nullptr, nullptr,qkvb,3072);
  rope_kernel<<<2048,256,0,stream>>>(qkvb, qb, kb);
  attn_kernel<<<dim3(32,16),256,0,stream>>>(qb, kb, qkvb+2048, 3072, ob);
  gemm_bt<1,false><<<dim3(8,16,KSO),256,0,stream>>>(ob,1024, outw,0,1024, 2048,1024,1024, KSO,(long long)2048*1024,
      nullptr,nullptr,nullptr,nullptr, x, x1p,nullptr,1024);
  rmsnorm2_kernel<<<2048,256,0,stream>>>(x1p, KSO, (long long)2048*1024, n2w, x1, h2b, h2f);
  router_kernel<<<2048,256,0,stream>>>(h2f, rw, probs, tope, topw, counts);
  prefix_kernel<<<1,64,0,stream>>>(counts, offs);
  scatter_kernel<<<8,256,0,stream>>>(tope, topw, offs, cursor, tok_list, wgt);
  gemm_bt<2,true><<<dim3(32,16,8),256,0,stream>>>(h2b,1024, w1,(long long)4096*1024,1024, 2048,4096,1024, 1,0,
      counts,offs,tok_list,nullptr,nullptr, nullptr,hid,4096);
  gemm_bt<3,false><<<dim3(8,16,8*KSW),256,0,stream>>>(hid,4096, w2,(long long)4096*1024,4096, 2048,1024,4096, KSW,(long long)4096*1024,
      counts,offs,tok_list,wgt,nullptr, slots,nullptr,1024);
  aux_kernel<<<1,256,0,stream>>>(probs, out);
  final_kernel<<<2048,256,0,stream>>>(x1, slots, KSW, (long long)4096*1024, out);
}